// Round 4
// baseline (312.480 us; speedup 1.0000x reference)
//
#include <hip/hip_runtime.h>
#include <hip/hip_bf16.h>
#include <math.h>

typedef __attribute__((ext_vector_type(8))) short bf16x8;
typedef __attribute__((ext_vector_type(4))) float f32x4;

#define S128 0.08838834764831845f   // 1/sqrt(128)
#define S96  0.10206207261596575f   // 1/sqrt(96)
#define S32  0.17677669529663687f   // 1/sqrt(32)
#define S64  0.125f                 // 1/sqrt(64)

__device__ __forceinline__ float silu_f(float x){ return x / (1.0f + expf(-x)); }
__device__ __forceinline__ ushort f2b(float x){
    __hip_bfloat16 b = __float2bfloat16(x); return *(ushort*)&b;
}
__device__ __forceinline__ float b2f(ushort u){
    return __uint_as_float(((uint)u) << 16);
}
__device__ __forceinline__ float blo(uint d){ return __uint_as_float(d << 16); }
__device__ __forceinline__ float bhi(uint d){ return __uint_as_float(d & 0xffff0000u); }
__device__ __forceinline__ uint packbf(float a, float b){
    return (uint)f2b(a) | ((uint)f2b(b) << 16);
}

// ---------------------------------------------------------------------------
// prep: WnT [32][128], W1T [128][96], W2T [128][128] (bf16 transposes)
// ---------------------------------------------------------------------------
__global__ __launch_bounds__(256)
void prep_weights(const float* __restrict__ Wn, const float* __restrict__ W1,
                  const float* __restrict__ W2, ushort* __restrict__ WnT,
                  ushort* __restrict__ W1T, ushort* __restrict__ W2T) {
    int idx = blockIdx.x * 256 + threadIdx.x;   // 128 blocks -> 32768
    if (idx < 4096) {
        int n = idx >> 7, k = idx & 127;
        WnT[n * 128 + k] = f2b(Wn[k * 32 + n]);
    } else if (idx < 16384) {
        int t = idx - 4096; int n = t / 96, k = t - n * 96;
        W1T[n * 96 + k] = f2b(W1[k * 128 + n]);
    } else {
        int t = idx - 16384; int n = t >> 7, k = t & 127;
        W2T[n * 128 + k] = f2b(W2[k * 128 + n]);
    }
}

// ---------------------------------------------------------------------------
// W3 [128][5120] f32 -> W3T [5120][128] bf16
// ---------------------------------------------------------------------------
__global__ __launch_bounds__(256)
void w3_transpose(const float* __restrict__ W3, ushort* __restrict__ w3t) {
    __shared__ float t[32][65];
    const int tid = threadIdx.x;
    const int cb = blockIdx.x * 64;
    const int kb = blockIdx.y * 32;
    #pragma unroll
    for (int it = 0; it < 8; ++it) {
        int idx = it * 256 + tid;
        int r = idx >> 6, c = idx & 63;
        t[r][c] = W3[(size_t)(kb + r) * 5120 + cb + c];
    }
    __syncthreads();
    #pragma unroll
    for (int it = 0; it < 8; ++it) {
        int idx = it * 256 + tid;
        int c = idx >> 5, k = idx & 31;
        w3t[(size_t)(cb + c) * 128 + kb + k] = f2b(t[k][c]);
    }
}

// ---------------------------------------------------------------------------
// MEGA: MLP -> GEMM(w)+contract -> finalize, one 64-edge block, 8 waves.
// d layout per edge (bf16, LDS stride 362):
//   d0 u@0 | d1 u*3+j@32 | d2 u@128 | d3 u*3+i@160 | d4 u*3+j@256
// ---------------------------------------------------------------------------
__global__ __launch_bounds__(512, 4)
void mega(const float* __restrict__ ef,  const float* __restrict__ em1,
          const float* __restrict__ em2, const float* __restrict__ nfs,
          const float* __restrict__ nfr, const ushort* __restrict__ WnT,
          const ushort* __restrict__ W1T, const ushort* __restrict__ W2T,
          const ushort* __restrict__ w3t, const float* __restrict__ W0e,
          const float* __restrict__ W1o, const float* __restrict__ W1e,
          float* __restrict__ out)
{
    __shared__ ushort dlds[64 * 362];   // 46336 B  (also MLP scratch)
    __shared__ ushort hbuf[64 * 132];   // 16896 B  h2s [64][128] / x1 [64][132]
    __shared__ uint   xp[64 * 68];      // 17408 B  packed bf16 x2 fragments

    const int tid  = threadIdx.x;
    const int lane = tid & 63, wv = tid >> 6;
    const int l15  = lane & 15, lg = lane >> 4;
    const int e0   = blockIdx.x * 64;

    ushort* scal = dlds;            // [64][104] bf16
    ushort* h1b  = dlds + 6656;     // [64][136] bf16

    // ---------- phase A: pack x2 (em2) into per-(e,lg) bf16 fragments ----------
    {
        int pid = tid >> 1, half = tid & 1;
        int e = pid >> 2, g = pid & 3;
        const float* x2 = em2 + (size_t)(e0 + e) * 128;
        if (half == 0) {
            float4 a = *(const float4*)(x2 + g * 4);
            float4 b = *(const float4*)(x2 + 16 + g * 4);
            uint4 w;
            w.x = packbf(a.x, a.y); w.y = packbf(a.z, a.w);
            w.z = packbf(b.x, b.y); w.w = packbf(b.z, b.w);
            *(uint4*)&xp[e * 68 + g * 16] = w;
        } else {
            float va[12], vb[12];
            #pragma unroll
            for (int q = 0; q < 6; ++q) {
                float2 t1 = *(const float2*)(x2 + 32 + g * 12 + q * 2);
                va[q * 2] = t1.x; va[q * 2 + 1] = t1.y;
                float2 t2 = *(const float2*)(x2 + 80 + g * 12 + q * 2);
                vb[q * 2] = t2.x; vb[q * 2 + 1] = t2.y;
            }
            #pragma unroll
            for (int j = 0; j < 3; ++j) {
                uint4 w;
                w.x = packbf(va[0 + j], va[3 + j]);
                w.y = packbf(va[6 + j], va[9 + j]);
                w.z = packbf(vb[0 + j], vb[3 + j]);
                w.w = packbf(vb[6 + j], vb[9 + j]);
                *(uint4*)&xp[e * 68 + g * 16 + 4 + j * 4] = w;
            }
        }
    }

    // ---------- phase B: ef -> scal cols 64..95 ----------
    #pragma unroll
    for (int q = 0; q < 4; ++q) {
        int idx = q * 512 + tid;         // 0..2047
        int e = idx >> 5, j = idx & 31;
        scal[e * 104 + 64 + j] = f2b(ef[(size_t)(e0 + e) * 32 + j]);
    }

    // ---------- MLP step 1: s_send/s_recv = nf @ Wn * S128 ----------
    {
        const int h = wv >> 2, eb = (wv & 3) * 16;
        const float* src = h ? nfr : nfs;
        const size_t erow = (size_t)(e0 + eb + l15) * 128;
        f32x4 acc1[2] = {{0,0,0,0},{0,0,0,0}};
        #pragma unroll
        for (int ks = 0; ks < 4; ++ks) {
            float4 va = *(const float4*)(src + erow + ks * 32 + lg * 8);
            float4 vb = *(const float4*)(src + erow + ks * 32 + lg * 8 + 4);
            bf16x8 a;
            a[0]=(short)f2b(va.x); a[1]=(short)f2b(va.y);
            a[2]=(short)f2b(va.z); a[3]=(short)f2b(va.w);
            a[4]=(short)f2b(vb.x); a[5]=(short)f2b(vb.y);
            a[6]=(short)f2b(vb.z); a[7]=(short)f2b(vb.w);
            #pragma unroll
            for (int nf = 0; nf < 2; ++nf) {
                bf16x8 b = *(const bf16x8*)(WnT + (nf * 16 + l15) * 128 + ks * 32 + lg * 8);
                acc1[nf] = __builtin_amdgcn_mfma_f32_16x16x32_bf16(a, b, acc1[nf], 0, 0, 0);
            }
        }
        #pragma unroll
        for (int nf = 0; nf < 2; ++nf)
            #pragma unroll
            for (int r = 0; r < 4; ++r)
                scal[(eb + lg * 4 + r) * 104 + h * 32 + nf * 16 + l15] =
                    f2b(acc1[nf][r] * S128);
    }
    __syncthreads();

    // ---------- MLP step 2: h1 = silu(scal @ W1 * S96) ----------
    {
        const int et = wv & 3, nh = wv >> 2;
        f32x4 acc2[4] = {{0,0,0,0},{0,0,0,0},{0,0,0,0},{0,0,0,0}};
        #pragma unroll
        for (int ks = 0; ks < 3; ++ks) {
            bf16x8 a = *(const bf16x8*)&scal[(et * 16 + l15) * 104 + ks * 32 + lg * 8];
            #pragma unroll
            for (int nf = 0; nf < 4; ++nf) {
                int gn = nh * 4 + nf;
                bf16x8 b = *(const bf16x8*)(W1T + (gn * 16 + l15) * 96 + ks * 32 + lg * 8);
                acc2[nf] = __builtin_amdgcn_mfma_f32_16x16x32_bf16(a, b, acc2[nf], 0, 0, 0);
            }
        }
        #pragma unroll
        for (int nf = 0; nf < 4; ++nf)
            #pragma unroll
            for (int r = 0; r < 4; ++r)
                h1b[(et * 16 + lg * 4 + r) * 136 + (nh * 4 + nf) * 16 + l15] =
                    f2b(silu_f(acc2[nf][r] * S96));
    }
    __syncthreads();

    // ---------- MLP step 3: h2 = silu(h1 @ W2 * S128), swizzled into hbuf ----------
    {
        const int et = wv & 3, nh = wv >> 2;
        f32x4 acc3[4] = {{0,0,0,0},{0,0,0,0},{0,0,0,0},{0,0,0,0}};
        #pragma unroll
        for (int ks = 0; ks < 4; ++ks) {
            bf16x8 a = *(const bf16x8*)&h1b[(et * 16 + l15) * 136 + ks * 32 + lg * 8];
            #pragma unroll
            for (int nf = 0; nf < 4; ++nf) {
                int gn = nh * 4 + nf;
                bf16x8 b = *(const bf16x8*)(W2T + (gn * 16 + l15) * 128 + ks * 32 + lg * 8);
                acc3[nf] = __builtin_amdgcn_mfma_f32_16x16x32_bf16(a, b, acc3[nf], 0, 0, 0);
            }
        }
        #pragma unroll
        for (int nf = 0; nf < 4; ++nf)
            #pragma unroll
            for (int r = 0; r < 4; ++r) {
                int e = et * 16 + lg * 4 + r;
                int col = (nh * 4 + nf) * 16 + l15;
                int chunk = (col >> 3) ^ (e & 15);
                hbuf[e * 128 + chunk * 8 + (col & 7)] =
                    f2b(silu_f(acc3[nf][r] * S128));
            }
    }
    __syncthreads();

    // ---------- GEMM + contraction: 10 M-tiles of 512 rows ----------
    #pragma unroll 1
    for (int mt = 0; mt < 10; ++mt) {
        const int mbase = mt * 512 + wv * 64;
        const int p = mbase >> 10;
        const int ubase = (mbase & 1023) >> 5;

        f32x4 acc[4][4];
        #pragma unroll
        for (int mi = 0; mi < 4; ++mi)
            #pragma unroll
            for (int nf = 0; nf < 4; ++nf)
                acc[mi][nf] = (f32x4){0.f, 0.f, 0.f, 0.f};

        bf16x8 a0[4], a1[4];
        #pragma unroll
        for (int mi = 0; mi < 4; ++mi)
            a0[mi] = *(const bf16x8*)(w3t + (size_t)(mbase + mi * 16 + l15) * 128 + lg * 8);

        #pragma unroll
        for (int ks = 0; ks < 4; ++ks) {
            bf16x8* ac = (ks & 1) ? a1 : a0;
            bf16x8* an = (ks & 1) ? a0 : a1;
            if (ks < 3) {
                #pragma unroll
                for (int mi = 0; mi < 4; ++mi)
                    an[mi] = *(const bf16x8*)(w3t
                        + (size_t)(mbase + mi * 16 + l15) * 128 + (ks + 1) * 32 + lg * 8);
            }
            #pragma unroll
            for (int nf = 0; nf < 4; ++nf) {
                int e = nf * 16 + l15;
                bf16x8 b = *(const bf16x8*)&hbuf[e * 128 + (((ks * 4 + lg) ^ l15) * 8)];
                #pragma unroll
                for (int mi = 0; mi < 4; ++mi)
                    acc[mi][nf] = __builtin_amdgcn_mfma_f32_16x16x32_bf16(
                        ac[mi], b, acc[mi][nf], 0, 0, 0);
            }
        }

        // tail: contract over v (rows) with packed x2, write d -> LDS
        if (p == 0 || p == 2) {
            const int off = (p == 0) ? 0 : 128;
            #pragma unroll
            for (int nf = 0; nf < 4; ++nf) {
                const int e = nf * 16 + l15;
                uint4 xq = *(const uint4*)&xp[e * 68 + lg * 16];
                float xa0 = blo(xq.x), xa1 = bhi(xq.x), xa2 = blo(xq.y), xa3 = bhi(xq.y);
                float xb0 = blo(xq.z), xb1 = bhi(xq.z), xb2 = blo(xq.w), xb3 = bhi(xq.w);
                #pragma unroll
                for (int g = 0; g < 2; ++g) {
                    f32x4 wa = acc[2 * g][nf], wb = acc[2 * g + 1][nf];
                    float s = wa[0]*xa0 + wa[1]*xa1 + wa[2]*xa2 + wa[3]*xa3
                            + wb[0]*xb0 + wb[1]*xb1 + wb[2]*xb2 + wb[3]*xb3;
                    s += __shfl_xor(s, 16);
                    s += __shfl_xor(s, 32);
                    if (lg == 0)
                        dlds[e * 362 + off + ubase + g] = f2b(s * S128);
                }
            }
        } else {
            const int off = (p == 1) ? 32 : (p == 3) ? 160 : 256;
            #pragma unroll
            for (int nf = 0; nf < 4; ++nf) {
                const int e = nf * 16 + l15;
                float s[2][3];
                #pragma unroll
                for (int j = 0; j < 3; ++j) {
                    uint4 xq = *(const uint4*)&xp[e * 68 + lg * 16 + 4 + j * 4];
                    float xa0 = blo(xq.x), xa1 = bhi(xq.x), xa2 = blo(xq.y), xa3 = bhi(xq.y);
                    float xb0 = blo(xq.z), xb1 = bhi(xq.z), xb2 = blo(xq.w), xb3 = bhi(xq.w);
                    #pragma unroll
                    for (int g = 0; g < 2; ++g) {
                        f32x4 wa = acc[2 * g][nf], wb = acc[2 * g + 1][nf];
                        s[g][j] = wa[0]*xa0 + wa[1]*xa1 + wa[2]*xa2 + wa[3]*xa3
                                + wb[0]*xb0 + wb[1]*xb1 + wb[2]*xb2 + wb[3]*xb3;
                    }
                }
                #pragma unroll
                for (int g = 0; g < 2; ++g)
                    #pragma unroll
                    for (int j = 0; j < 3; ++j) {
                        float sv = s[g][j];
                        sv += __shfl_xor(sv, 16);
                        sv += __shfl_xor(sv, 32);
                        if (lg == 0)
                            dlds[e * 362 + off + (ubase + g) * 3 + j] = f2b(sv * S128);
                    }
            }
        }
    }
    __syncthreads();

    // ---------- stage x1 (em1) bf16 into hbuf [64][132] ----------
    {
        int e = tid >> 3, seg = tid & 7;
        const float* x1 = em1 + (size_t)(e0 + e) * 128 + seg * 16;
        #pragma unroll
        for (int q = 0; q < 4; ++q) {
            float4 v = *(const float4*)(x1 + q * 4);
            *(uint*)&hbuf[e * 132 + seg * 16 + q * 4]     = packbf(v.x, v.y);
            *(uint*)&hbuf[e * 132 + seg * 16 + q * 4 + 2] = packbf(v.z, v.w);
        }
    }
    __syncthreads();

    // ---------- finalize: c-values -> output matmuls via MFMA ----------
    #pragma unroll 1
    for (int it = 0; it < 4; ++it) {
        int unit = wv + 8 * it;
        if (unit >= 28) break;
        int mi = unit & 3, task = unit >> 2;
        int e = mi * 16 + l15;
        const ushort* de = &dlds[e * 362];
        const ushort* xe = &hbuf[e * 132];
        const size_t orow = (size_t)(e0 + mi * 16 + lg * 4) * 224;

        if (task == 0) {                       // out_0e: K = [c1|c4]
            bf16x8 af0, af1;
            #pragma unroll
            for (int t = 0; t < 8; ++t) {
                int u = lg * 8 + t;
                af0[t] = (short)f2b(S32 * b2f(xe[u]) * b2f(de[u]));
                float c4 = 0.f;
                #pragma unroll
                for (int i = 0; i < 3; ++i)
                    c4 += b2f(xe[32 + u * 3 + i]) * b2f(de[160 + u * 3 + i]);
                af1[t] = (short)f2b(c4 * S96);
            }
            #pragma unroll
            for (int nf = 0; nf < 2; ++nf) {
                bf16x8 bf0, bf1;
                #pragma unroll
                for (int t = 0; t < 8; ++t) {
                    bf0[t] = (short)f2b(W0e[(lg * 8 + t) * 32 + nf * 16 + l15]);
                    bf1[t] = (short)f2b(W0e[(32 + lg * 8 + t) * 32 + nf * 16 + l15]);
                }
                f32x4 o = {0.f, 0.f, 0.f, 0.f};
                o = __builtin_amdgcn_mfma_f32_16x16x32_bf16(af0, bf0, o, 0, 0, 0);
                o = __builtin_amdgcn_mfma_f32_16x16x32_bf16(af1, bf1, o, 0, 0, 0);
                #pragma unroll
                for (int rr = 0; rr < 4; ++rr)
                    out[orow + (size_t)rr * 224 + nf * 16 + l15] = o[rr] * S64;
            }
        } else if (task <= 3) {                // out_1o, j = task-1: K = [c2|c3]
            int j = task - 1;
            bf16x8 af0, af1;
            #pragma unroll
            for (int t = 0; t < 8; ++t) {
                int u = lg * 8 + t;
                af0[t] = (short)f2b(S32 * b2f(xe[u]) * b2f(de[32 + u * 3 + j]));
                af1[t] = (short)f2b(S32 * b2f(xe[32 + u * 3 + j]) * b2f(de[128 + u]));
            }
            #pragma unroll
            for (int nf = 0; nf < 2; ++nf) {
                bf16x8 bf0, bf1;
                #pragma unroll
                for (int t = 0; t < 8; ++t) {
                    bf0[t] = (short)f2b(W1o[(lg * 8 + t) * 32 + nf * 16 + l15]);
                    bf1[t] = (short)f2b(W1o[(32 + lg * 8 + t) * 32 + nf * 16 + l15]);
                }
                f32x4 o = {0.f, 0.f, 0.f, 0.f};
                o = __builtin_amdgcn_mfma_f32_16x16x32_bf16(af0, bf0, o, 0, 0, 0);
                o = __builtin_amdgcn_mfma_f32_16x16x32_bf16(af1, bf1, o, 0, 0, 0);
                #pragma unroll
                for (int rr = 0; rr < 4; ++rr)
                    out[orow + (size_t)rr * 224 + 32 + (nf * 16 + l15) * 3 + j] = o[rr] * S64;
            }
        } else {                               // out_1e, k = task-4: K = c5 (32)
            int k = task - 4;
            int k1 = k + 1; if (k1 > 2) k1 -= 3;
            int k2 = k + 2; if (k2 > 2) k2 -= 3;
            bf16x8 af0;
            #pragma unroll
            for (int t = 0; t < 8; ++t) {
                int u = lg * 8 + t;        // 0..31
                float a_ = b2f(xe[32 + u * 3 + k1]) * b2f(de[256 + u * 3 + k2])
                         - b2f(xe[32 + u * 3 + k2]) * b2f(de[256 + u * 3 + k1]);
                af0[t] = (short)f2b(a_ * S64);
            }
            #pragma unroll
            for (int nf = 0; nf < 2; ++nf) {
                bf16x8 bf0;
                #pragma unroll
                for (int t = 0; t < 8; ++t)
                    bf0[t] = (short)f2b(W1e[(lg * 8 + t) * 32 + nf * 16 + l15]);
                f32x4 o = {0.f, 0.f, 0.f, 0.f};
                o = __builtin_amdgcn_mfma_f32_16x16x32_bf16(af0, bf0, o, 0, 0, 0);
                #pragma unroll
                for (int rr = 0; rr < 4; ++rr)
                    out[orow + (size_t)rr * 224 + 128 + (nf * 16 + l15) * 3 + k] = o[rr] * S32;
            }
        }
    }
}

// ---------------------------------------------------------------------------
extern "C" void kernel_launch(void* const* d_in, const int* in_sizes, int n_in,
                              void* d_out, int out_size, void* d_ws, size_t ws_size,
                              hipStream_t stream) {
    const float* ef  = (const float*)d_in[0];
    const float* em1 = (const float*)d_in[1];
    const float* em2 = (const float*)d_in[2];
    const float* nfs = (const float*)d_in[3];
    const float* nfr = (const float*)d_in[4];
    const float* Wn  = (const float*)d_in[5];
    const float* W1  = (const float*)d_in[6];
    const float* W2  = (const float*)d_in[7];
    const float* W3  = (const float*)d_in[8];
    const float* W0e = (const float*)d_in[9];
    const float* W1o = (const float*)d_in[10];
    const float* W1e = (const float*)d_in[11];
    float* out = (float*)d_out;

    const int E = in_sizes[0] / 32;   // 40000

    // ws: w3t [5120][128] | WnT [32][128] | W1T [128][96] | W2T [128][128]
    char* ws = (char*)d_ws;
    ushort* w3t = (ushort*)ws;
    size_t off = (size_t)5120 * 128 * 2;
    ushort* WnT = (ushort*)(ws + off);  off += 32 * 128 * 2;
    ushort* W1T = (ushort*)(ws + off);  off += 128 * 96 * 2;
    ushort* W2T = (ushort*)(ws + off);

    prep_weights<<<128, 256, 0, stream>>>(Wn, W1, W2, WnT, W1T, W2T);
    w3_transpose<<<dim3(80, 4), 256, 0, stream>>>(W3, w3t);
    mega<<<E / 64, 512, 0, stream>>>(ef, em1, em2, nfs, nfr,
                                     WnT, W1T, W2T, w3t, W0e, W1o, W1e, out);
}

// Round 5
// 197.971 us; speedup vs baseline: 1.5784x; 1.5784x over previous
//
#include <hip/hip_runtime.h>
#include <hip/hip_bf16.h>
#include <math.h>

typedef __attribute__((ext_vector_type(8))) short bf16x8;
typedef __attribute__((ext_vector_type(4))) float f32x4;

#define S128 0.08838834764831845f   // 1/sqrt(128)
#define S96  0.10206207261596575f   // 1/sqrt(96)
#define S32  0.17677669529663687f   // 1/sqrt(32)
#define S64  0.125f                 // 1/sqrt(64)

__device__ __forceinline__ float silu_f(float x){ return x / (1.0f + expf(-x)); }
__device__ __forceinline__ ushort f2b(float x){
    __hip_bfloat16 b = __float2bfloat16(x); return *(ushort*)&b;
}
__device__ __forceinline__ float b2f(ushort u){
    return __uint_as_float(((uint)u) << 16);
}
__device__ __forceinline__ float blo(uint d){ return __uint_as_float(d << 16); }
__device__ __forceinline__ float bhi(uint d){ return __uint_as_float(d & 0xffff0000u); }
__device__ __forceinline__ uint packbf(float a, float b){
    return (uint)f2b(a) | ((uint)f2b(b) << 16);
}

// ---------------------------------------------------------------------------
// prep: WnT [32][128], W1T [128][96], W2T [128][128] (bf16 transposes)
// ---------------------------------------------------------------------------
__global__ __launch_bounds__(256)
void prep_weights(const float* __restrict__ Wn, const float* __restrict__ W1,
                  const float* __restrict__ W2, ushort* __restrict__ WnT,
                  ushort* __restrict__ W1T, ushort* __restrict__ W2T) {
    int idx = blockIdx.x * 256 + threadIdx.x;   // 128 blocks -> 32768
    if (idx < 4096) {
        int n = idx >> 7, k = idx & 127;
        WnT[n * 128 + k] = f2b(Wn[k * 32 + n]);
    } else if (idx < 16384) {
        int t = idx - 4096; int n = t / 96, k = t - n * 96;
        W1T[n * 96 + k] = f2b(W1[k * 128 + n]);
    } else {
        int t = idx - 16384; int n = t >> 7, k = t & 127;
        W2T[n * 128 + k] = f2b(W2[k * 128 + n]);
    }
}

// ---------------------------------------------------------------------------
// W3 [128][5120] f32 -> W3T [5120][128] bf16
// ---------------------------------------------------------------------------
__global__ __launch_bounds__(256)
void w3_transpose(const float* __restrict__ W3, ushort* __restrict__ w3t) {
    __shared__ float t[32][65];
    const int tid = threadIdx.x;
    const int cb = blockIdx.x * 64;
    const int kb = blockIdx.y * 32;
    #pragma unroll
    for (int it = 0; it < 8; ++it) {
        int idx = it * 256 + tid;
        int r = idx >> 6, c = idx & 63;
        t[r][c] = W3[(size_t)(kb + r) * 5120 + cb + c];
    }
    __syncthreads();
    #pragma unroll
    for (int it = 0; it < 8; ++it) {
        int idx = it * 256 + tid;
        int c = idx >> 5, k = idx & 31;
        w3t[(size_t)(cb + c) * 128 + kb + k] = f2b(t[k][c]);
    }
}

// ---------------------------------------------------------------------------
// MEGA: MLP -> GEMM(w)+contract -> finalize, one 64-edge block, 8 waves.
// d layout per edge (bf16, LDS stride 362):
//   d0 u@0 | d1 u*3+j@32 | d2 u@128 | d3 u*3+i@160 | d4 u*3+j@256
// ---------------------------------------------------------------------------
__global__ __launch_bounds__(512, 2)
void mega(const float* __restrict__ ef,  const float* __restrict__ em1,
          const float* __restrict__ em2, const float* __restrict__ nfs,
          const float* __restrict__ nfr, const ushort* __restrict__ WnT,
          const ushort* __restrict__ W1T, const ushort* __restrict__ W2T,
          const ushort* __restrict__ w3t, const float* __restrict__ W0e,
          const float* __restrict__ W1o, const float* __restrict__ W1e,
          float* __restrict__ out)
{
    __shared__ ushort dlds[64 * 362];   // 46336 B  (also MLP scratch)
    __shared__ ushort hbuf[64 * 132];   // 16896 B  h2s [64][128] / x1 [64][132]
    __shared__ uint   xp[64 * 68];      // 17408 B  packed bf16 x2 fragments

    const int tid  = threadIdx.x;
    const int lane = tid & 63, wv = tid >> 6;
    const int l15  = lane & 15, lg = lane >> 4;
    const int e0   = blockIdx.x * 64;

    ushort* scal = dlds;            // [64][104] bf16
    ushort* h1b  = dlds + 6656;     // [64][136] bf16

    // ---------- phase A: pack x2 (em2) into per-(e,lg) bf16 fragments ----------
    {
        int pid = tid >> 1, half = tid & 1;
        int e = pid >> 2, g = pid & 3;
        const float* x2 = em2 + (size_t)(e0 + e) * 128;
        if (half == 0) {
            float4 a = *(const float4*)(x2 + g * 4);
            float4 b = *(const float4*)(x2 + 16 + g * 4);
            uint4 w;
            w.x = packbf(a.x, a.y); w.y = packbf(a.z, a.w);
            w.z = packbf(b.x, b.y); w.w = packbf(b.z, b.w);
            *(uint4*)&xp[e * 68 + g * 16] = w;
        } else {
            float va[12], vb[12];
            #pragma unroll
            for (int q = 0; q < 6; ++q) {
                float2 t1 = *(const float2*)(x2 + 32 + g * 12 + q * 2);
                va[q * 2] = t1.x; va[q * 2 + 1] = t1.y;
                float2 t2 = *(const float2*)(x2 + 80 + g * 12 + q * 2);
                vb[q * 2] = t2.x; vb[q * 2 + 1] = t2.y;
            }
            #pragma unroll
            for (int j = 0; j < 3; ++j) {
                uint4 w;
                w.x = packbf(va[0 + j], va[3 + j]);
                w.y = packbf(va[6 + j], va[9 + j]);
                w.z = packbf(vb[0 + j], vb[3 + j]);
                w.w = packbf(vb[6 + j], vb[9 + j]);
                *(uint4*)&xp[e * 68 + g * 16 + 4 + j * 4] = w;
            }
        }
    }

    // ---------- phase B: ef -> scal cols 64..95 ----------
    #pragma unroll
    for (int q = 0; q < 4; ++q) {
        int idx = q * 512 + tid;         // 0..2047
        int e = idx >> 5, j = idx & 31;
        scal[e * 104 + 64 + j] = f2b(ef[(size_t)(e0 + e) * 32 + j]);
    }

    // ---------- MLP step 1: s_send/s_recv = nf @ Wn * S128 ----------
    {
        const int h = wv >> 2, eb = (wv & 3) * 16;
        const float* src = h ? nfr : nfs;
        const size_t erow = (size_t)(e0 + eb + l15) * 128;
        f32x4 acc1[2] = {{0,0,0,0},{0,0,0,0}};
        #pragma unroll
        for (int ks = 0; ks < 4; ++ks) {
            float4 va = *(const float4*)(src + erow + ks * 32 + lg * 8);
            float4 vb = *(const float4*)(src + erow + ks * 32 + lg * 8 + 4);
            bf16x8 a;
            a[0]=(short)f2b(va.x); a[1]=(short)f2b(va.y);
            a[2]=(short)f2b(va.z); a[3]=(short)f2b(va.w);
            a[4]=(short)f2b(vb.x); a[5]=(short)f2b(vb.y);
            a[6]=(short)f2b(vb.z); a[7]=(short)f2b(vb.w);
            #pragma unroll
            for (int nf = 0; nf < 2; ++nf) {
                bf16x8 b = *(const bf16x8*)(WnT + (nf * 16 + l15) * 128 + ks * 32 + lg * 8);
                acc1[nf] = __builtin_amdgcn_mfma_f32_16x16x32_bf16(a, b, acc1[nf], 0, 0, 0);
            }
        }
        #pragma unroll
        for (int nf = 0; nf < 2; ++nf)
            #pragma unroll
            for (int r = 0; r < 4; ++r)
                scal[(eb + lg * 4 + r) * 104 + h * 32 + nf * 16 + l15] =
                    f2b(acc1[nf][r] * S128);
    }
    __syncthreads();

    // ---------- MLP step 2: h1 = silu(scal @ W1 * S96) ----------
    {
        const int et = wv & 3, nh = wv >> 2;
        f32x4 acc2[4] = {{0,0,0,0},{0,0,0,0},{0,0,0,0},{0,0,0,0}};
        #pragma unroll
        for (int ks = 0; ks < 3; ++ks) {
            bf16x8 a = *(const bf16x8*)&scal[(et * 16 + l15) * 104 + ks * 32 + lg * 8];
            #pragma unroll
            for (int nf = 0; nf < 4; ++nf) {
                int gn = nh * 4 + nf;
                bf16x8 b = *(const bf16x8*)(W1T + (gn * 16 + l15) * 96 + ks * 32 + lg * 8);
                acc2[nf] = __builtin_amdgcn_mfma_f32_16x16x32_bf16(a, b, acc2[nf], 0, 0, 0);
            }
        }
        #pragma unroll
        for (int nf = 0; nf < 4; ++nf)
            #pragma unroll
            for (int r = 0; r < 4; ++r)
                h1b[(et * 16 + lg * 4 + r) * 136 + (nh * 4 + nf) * 16 + l15] =
                    f2b(silu_f(acc2[nf][r] * S96));
    }
    __syncthreads();

    // ---------- MLP step 3: h2 = silu(h1 @ W2 * S128), swizzled into hbuf ----------
    {
        const int et = wv & 3, nh = wv >> 2;
        f32x4 acc3[4] = {{0,0,0,0},{0,0,0,0},{0,0,0,0},{0,0,0,0}};
        #pragma unroll
        for (int ks = 0; ks < 4; ++ks) {
            bf16x8 a = *(const bf16x8*)&h1b[(et * 16 + l15) * 136 + ks * 32 + lg * 8];
            #pragma unroll
            for (int nf = 0; nf < 4; ++nf) {
                int gn = nh * 4 + nf;
                bf16x8 b = *(const bf16x8*)(W2T + (gn * 16 + l15) * 128 + ks * 32 + lg * 8);
                acc3[nf] = __builtin_amdgcn_mfma_f32_16x16x32_bf16(a, b, acc3[nf], 0, 0, 0);
            }
        }
        #pragma unroll
        for (int nf = 0; nf < 4; ++nf)
            #pragma unroll
            for (int r = 0; r < 4; ++r) {
                int e = et * 16 + lg * 4 + r;
                int col = (nh * 4 + nf) * 16 + l15;
                int chunk = (col >> 3) ^ (e & 15);
                hbuf[e * 128 + chunk * 8 + (col & 7)] =
                    f2b(silu_f(acc3[nf][r] * S128));
            }
    }
    __syncthreads();

    // ---------- GEMM + contraction: 10 M-tiles of 512 rows ----------
    #pragma unroll 1
    for (int mt = 0; mt < 10; ++mt) {
        const int mbase = mt * 512 + wv * 64;
        const int p = mbase >> 10;
        const int ubase = (mbase & 1023) >> 5;

        f32x4 acc[4][4];
        #pragma unroll
        for (int mi = 0; mi < 4; ++mi)
            #pragma unroll
            for (int nf = 0; nf < 4; ++nf)
                acc[mi][nf] = (f32x4){0.f, 0.f, 0.f, 0.f};

        bf16x8 a0[4], a1[4];
        #pragma unroll
        for (int mi = 0; mi < 4; ++mi)
            a0[mi] = *(const bf16x8*)(w3t + (size_t)(mbase + mi * 16 + l15) * 128 + lg * 8);

        #pragma unroll
        for (int ks = 0; ks < 4; ++ks) {
            bf16x8* ac = (ks & 1) ? a1 : a0;
            bf16x8* an = (ks & 1) ? a0 : a1;
            if (ks < 3) {
                #pragma unroll
                for (int mi = 0; mi < 4; ++mi)
                    an[mi] = *(const bf16x8*)(w3t
                        + (size_t)(mbase + mi * 16 + l15) * 128 + (ks + 1) * 32 + lg * 8);
            }
            #pragma unroll
            for (int nf = 0; nf < 4; ++nf) {
                int e = nf * 16 + l15;
                bf16x8 b = *(const bf16x8*)&hbuf[e * 128 + (((ks * 4 + lg) ^ l15) * 8)];
                #pragma unroll
                for (int mi = 0; mi < 4; ++mi)
                    acc[mi][nf] = __builtin_amdgcn_mfma_f32_16x16x32_bf16(
                        ac[mi], b, acc[mi][nf], 0, 0, 0);
            }
        }

        // tail: contract over v (rows) with packed x2, write d -> LDS
        if (p == 0 || p == 2) {
            const int off = (p == 0) ? 0 : 128;
            #pragma unroll
            for (int nf = 0; nf < 4; ++nf) {
                const int e = nf * 16 + l15;
                uint4 xq = *(const uint4*)&xp[e * 68 + lg * 16];
                float xa0 = blo(xq.x), xa1 = bhi(xq.x), xa2 = blo(xq.y), xa3 = bhi(xq.y);
                float xb0 = blo(xq.z), xb1 = bhi(xq.z), xb2 = blo(xq.w), xb3 = bhi(xq.w);
                #pragma unroll
                for (int g = 0; g < 2; ++g) {
                    f32x4 wa = acc[2 * g][nf], wb = acc[2 * g + 1][nf];
                    float s = wa[0]*xa0 + wa[1]*xa1 + wa[2]*xa2 + wa[3]*xa3
                            + wb[0]*xb0 + wb[1]*xb1 + wb[2]*xb2 + wb[3]*xb3;
                    s += __shfl_xor(s, 16);
                    s += __shfl_xor(s, 32);
                    if (lg == 0)
                        dlds[e * 362 + off + ubase + g] = f2b(s * S128);
                }
            }
        } else {
            const int off = (p == 1) ? 32 : (p == 3) ? 160 : 256;
            #pragma unroll
            for (int nf = 0; nf < 4; ++nf) {
                const int e = nf * 16 + l15;
                float s[2][3];
                #pragma unroll
                for (int j = 0; j < 3; ++j) {
                    uint4 xq = *(const uint4*)&xp[e * 68 + lg * 16 + 4 + j * 4];
                    float xa0 = blo(xq.x), xa1 = bhi(xq.x), xa2 = blo(xq.y), xa3 = bhi(xq.y);
                    float xb0 = blo(xq.z), xb1 = bhi(xq.z), xb2 = blo(xq.w), xb3 = bhi(xq.w);
                    #pragma unroll
                    for (int g = 0; g < 2; ++g) {
                        f32x4 wa = acc[2 * g][nf], wb = acc[2 * g + 1][nf];
                        s[g][j] = wa[0]*xa0 + wa[1]*xa1 + wa[2]*xa2 + wa[3]*xa3
                                + wb[0]*xb0 + wb[1]*xb1 + wb[2]*xb2 + wb[3]*xb3;
                    }
                }
                #pragma unroll
                for (int g = 0; g < 2; ++g)
                    #pragma unroll
                    for (int j = 0; j < 3; ++j) {
                        float sv = s[g][j];
                        sv += __shfl_xor(sv, 16);
                        sv += __shfl_xor(sv, 32);
                        if (lg == 0)
                            dlds[e * 362 + off + (ubase + g) * 3 + j] = f2b(sv * S128);
                    }
            }
        }
    }
    __syncthreads();

    // ---------- stage x1 (em1) bf16 into hbuf [64][132] ----------
    {
        int e = tid >> 3, seg = tid & 7;
        const float* x1 = em1 + (size_t)(e0 + e) * 128 + seg * 16;
        #pragma unroll
        for (int q = 0; q < 4; ++q) {
            float4 v = *(const float4*)(x1 + q * 4);
            *(uint*)&hbuf[e * 132 + seg * 16 + q * 4]     = packbf(v.x, v.y);
            *(uint*)&hbuf[e * 132 + seg * 16 + q * 4 + 2] = packbf(v.z, v.w);
        }
    }
    __syncthreads();

    // ---------- finalize: c-values -> output matmuls via MFMA ----------
    #pragma unroll 1
    for (int it = 0; it < 4; ++it) {
        int unit = wv + 8 * it;
        if (unit >= 28) break;
        int mi = unit & 3, task = unit >> 2;
        int e = mi * 16 + l15;
        const ushort* de = &dlds[e * 362];
        const ushort* xe = &hbuf[e * 132];
        const size_t orow = (size_t)(e0 + mi * 16 + lg * 4) * 224;

        if (task == 0) {                       // out_0e: K = [c1|c4]
            bf16x8 af0, af1;
            #pragma unroll
            for (int t = 0; t < 8; ++t) {
                int u = lg * 8 + t;
                af0[t] = (short)f2b(S32 * b2f(xe[u]) * b2f(de[u]));
                float c4 = 0.f;
                #pragma unroll
                for (int i = 0; i < 3; ++i)
                    c4 += b2f(xe[32 + u * 3 + i]) * b2f(de[160 + u * 3 + i]);
                af1[t] = (short)f2b(c4 * S96);
            }
            #pragma unroll
            for (int nf = 0; nf < 2; ++nf) {
                bf16x8 bf0, bf1;
                #pragma unroll
                for (int t = 0; t < 8; ++t) {
                    bf0[t] = (short)f2b(W0e[(lg * 8 + t) * 32 + nf * 16 + l15]);
                    bf1[t] = (short)f2b(W0e[(32 + lg * 8 + t) * 32 + nf * 16 + l15]);
                }
                f32x4 o = {0.f, 0.f, 0.f, 0.f};
                o = __builtin_amdgcn_mfma_f32_16x16x32_bf16(af0, bf0, o, 0, 0, 0);
                o = __builtin_amdgcn_mfma_f32_16x16x32_bf16(af1, bf1, o, 0, 0, 0);
                #pragma unroll
                for (int rr = 0; rr < 4; ++rr)
                    out[orow + (size_t)rr * 224 + nf * 16 + l15] = o[rr] * S64;
            }
        } else if (task <= 3) {                // out_1o, j = task-1: K = [c2|c3]
            int j = task - 1;
            bf16x8 af0, af1;
            #pragma unroll
            for (int t = 0; t < 8; ++t) {
                int u = lg * 8 + t;
                af0[t] = (short)f2b(S32 * b2f(xe[u]) * b2f(de[32 + u * 3 + j]));
                af1[t] = (short)f2b(S32 * b2f(xe[32 + u * 3 + j]) * b2f(de[128 + u]));
            }
            #pragma unroll
            for (int nf = 0; nf < 2; ++nf) {
                bf16x8 bf0, bf1;
                #pragma unroll
                for (int t = 0; t < 8; ++t) {
                    bf0[t] = (short)f2b(W1o[(lg * 8 + t) * 32 + nf * 16 + l15]);
                    bf1[t] = (short)f2b(W1o[(32 + lg * 8 + t) * 32 + nf * 16 + l15]);
                }
                f32x4 o = {0.f, 0.f, 0.f, 0.f};
                o = __builtin_amdgcn_mfma_f32_16x16x32_bf16(af0, bf0, o, 0, 0, 0);
                o = __builtin_amdgcn_mfma_f32_16x16x32_bf16(af1, bf1, o, 0, 0, 0);
                #pragma unroll
                for (int rr = 0; rr < 4; ++rr)
                    out[orow + (size_t)rr * 224 + 32 + (nf * 16 + l15) * 3 + j] = o[rr] * S64;
            }
        } else {                               // out_1e, k = task-4: K = c5 (32)
            int k = task - 4;
            int k1 = k + 1; if (k1 > 2) k1 -= 3;
            int k2 = k + 2; if (k2 > 2) k2 -= 3;
            bf16x8 af0;
            #pragma unroll
            for (int t = 0; t < 8; ++t) {
                int u = lg * 8 + t;        // 0..31
                float a_ = b2f(xe[32 + u * 3 + k1]) * b2f(de[256 + u * 3 + k2])
                         - b2f(xe[32 + u * 3 + k2]) * b2f(de[256 + u * 3 + k1]);
                af0[t] = (short)f2b(a_ * S64);
            }
            #pragma unroll
            for (int nf = 0; nf < 2; ++nf) {
                bf16x8 bf0;
                #pragma unroll
                for (int t = 0; t < 8; ++t)
                    bf0[t] = (short)f2b(W1e[(lg * 8 + t) * 32 + nf * 16 + l15]);
                f32x4 o = {0.f, 0.f, 0.f, 0.f};
                o = __builtin_amdgcn_mfma_f32_16x16x32_bf16(af0, bf0, o, 0, 0, 0);
                #pragma unroll
                for (int rr = 0; rr < 4; ++rr)
                    out[orow + (size_t)rr * 224 + 128 + (nf * 16 + l15) * 3 + k] = o[rr] * S32;
            }
        }
    }
}

// ---------------------------------------------------------------------------
extern "C" void kernel_launch(void* const* d_in, const int* in_sizes, int n_in,
                              void* d_out, int out_size, void* d_ws, size_t ws_size,
                              hipStream_t stream) {
    const float* ef  = (const float*)d_in[0];
    const float* em1 = (const float*)d_in[1];
    const float* em2 = (const float*)d_in[2];
    const float* nfs = (const float*)d_in[3];
    const float* nfr = (const float*)d_in[4];
    const float* Wn  = (const float*)d_in[5];
    const float* W1  = (const float*)d_in[6];
    const float* W2  = (const float*)d_in[7];
    const float* W3  = (const float*)d_in[8];
    const float* W0e = (const float*)d_in[9];
    const float* W1o = (const float*)d_in[10];
    const float* W1e = (const float*)d_in[11];
    float* out = (float*)d_out;

    const int E = in_sizes[0] / 32;   // 40000

    // ws: w3t [5120][128] | WnT [32][128] | W1T [128][96] | W2T [128][128]
    char* ws = (char*)d_ws;
    ushort* w3t = (ushort*)ws;
    size_t off = (size_t)5120 * 128 * 2;
    ushort* WnT = (ushort*)(ws + off);  off += 32 * 128 * 2;
    ushort* W1T = (ushort*)(ws + off);  off += 128 * 96 * 2;
    ushort* W2T = (ushort*)(ws + off);

    prep_weights<<<128, 256, 0, stream>>>(Wn, W1, W2, WnT, W1T, W2T);
    w3_transpose<<<dim3(80, 4), 256, 0, stream>>>(W3, w3t);
    mega<<<E / 64, 512, 0, stream>>>(ef, em1, em2, nfs, nfr,
                                     WnT, W1T, W2T, w3t, W0e, W1o, W1e, out);
}

// Round 6
// 168.160 us; speedup vs baseline: 1.8582x; 1.1773x over previous
//
#include <hip/hip_runtime.h>
#include <hip/hip_bf16.h>
#include <math.h>

typedef __attribute__((ext_vector_type(8)))  short bf16x8;
typedef __attribute__((ext_vector_type(4)))  float f32x4;
typedef __attribute__((ext_vector_type(16))) float f32x16;

#define S128 0.08838834764831845f   // 1/sqrt(128)
#define S96  0.10206207261596575f   // 1/sqrt(96)
#define S32  0.17677669529663687f   // 1/sqrt(32)
#define S64  0.125f                 // 1/sqrt(64)

__device__ __forceinline__ float silu_f(float x){ return x / (1.0f + expf(-x)); }
__device__ __forceinline__ ushort f2b(float x){
    __hip_bfloat16 b = __float2bfloat16(x); return *(ushort*)&b;
}
__device__ __forceinline__ float b2f(ushort u){
    return __uint_as_float(((uint)u) << 16);
}
__device__ __forceinline__ float blo(uint d){ return __uint_as_float(d << 16); }
__device__ __forceinline__ float bhi(uint d){ return __uint_as_float(d & 0xffff0000u); }
__device__ __forceinline__ uint packbf(float a, float b){
    return (uint)f2b(a) | ((uint)f2b(b) << 16);
}

// ---------------------------------------------------------------------------
// prep: WnT [32][128], W1T [128][96], W2T [128][128] (bf16 transposes)
// ---------------------------------------------------------------------------
__global__ __launch_bounds__(256)
void prep_weights(const float* __restrict__ Wn, const float* __restrict__ W1,
                  const float* __restrict__ W2, ushort* __restrict__ WnT,
                  ushort* __restrict__ W1T, ushort* __restrict__ W2T) {
    int idx = blockIdx.x * 256 + threadIdx.x;   // 128 blocks -> 32768
    if (idx < 4096) {
        int n = idx >> 7, k = idx & 127;
        WnT[n * 128 + k] = f2b(Wn[k * 32 + n]);
    } else if (idx < 16384) {
        int t = idx - 4096; int n = t / 96, k = t - n * 96;
        W1T[n * 96 + k] = f2b(W1[k * 128 + n]);
    } else {
        int t = idx - 16384; int n = t >> 7, k = t & 127;
        W2T[n * 128 + k] = f2b(W2[k * 128 + n]);
    }
}

// ---------------------------------------------------------------------------
// W3 [128][5120] f32 -> w3A fragment-major bf16:
//   w3A[((pu*8 + ks)*64 + lane)*8 + i] = W3[k][m],
//   m = pu*32 + (lane&31), k = ks*16 + (lane>>5)*8 + i
// One block per pu (160 blocks).
// ---------------------------------------------------------------------------
__global__ __launch_bounds__(256)
void w3_fragpack(const float* __restrict__ W3, ushort* __restrict__ w3A) {
    const int pu = blockIdx.x;
    const int t  = threadIdx.x;
    #pragma unroll
    for (int s = 0; s < 2; ++s) {
        int slot = s * 256 + t;          // 0..511
        int ks = slot >> 6, l = slot & 63;
        int m = pu * 32 + (l & 31);
        int kbase = ks * 16 + (l >> 5) * 8;
        bf16x8 v;
        #pragma unroll
        for (int i = 0; i < 8; ++i)
            v[i] = (short)f2b(W3[(size_t)(kbase + i) * 5120 + m]);
        *(bf16x8*)&w3A[((size_t)(pu * 8 + ks) * 64 + l) * 8] = v;
    }
}

// ---------------------------------------------------------------------------
// MEGA: MLP -> GEMM(32x32 units)+contract -> finalize. 64 edges/block, 8 waves.
// d layout per edge (bf16, LDS stride 362):
//   d0 u@0 | d1 u*3+j@32 | d2 u@128 | d3 u*3+i@160 | d4 u*3+j@256
// ---------------------------------------------------------------------------
__global__ __launch_bounds__(512, 2)
void mega(const float* __restrict__ ef,  const float* __restrict__ em1,
          const float* __restrict__ em2, const float* __restrict__ nfs,
          const float* __restrict__ nfr, const ushort* __restrict__ WnT,
          const ushort* __restrict__ W1T, const ushort* __restrict__ W2T,
          const ushort* __restrict__ w3A, const float* __restrict__ W0e,
          const float* __restrict__ W1o, const float* __restrict__ W1e,
          float* __restrict__ out)
{
    __shared__ __align__(16) ushort dlds[64 * 362]; // 46336 B (also scratch)
    __shared__ __align__(16) ushort hbuf[64 * 132]; // 16896 B h2s / x1
    __shared__ __align__(16) uint   xp2[2 * 64 * 34]; // 17408 B packed x2 pairs

    const int tid  = threadIdx.x;
    const int lane = tid & 63, wv = tid >> 6;
    const int l15  = lane & 15, lg = lane >> 4;
    const int e0   = blockIdx.x * 64;

    ushort* scal = dlds;            // [64][104] bf16 (after x2f scratch freed)
    ushort* h1b  = dlds + 6656;     // [64][136] bf16
    float*  x2f  = (float*)dlds;    // [64][132] f32 scratch (phase A only)

    // ---------- phase A1: stage em2 tile -> x2f (coalesced) ----------
    #pragma unroll
    for (int q = 0; q < 4; ++q) {
        int idx = q * 512 + tid;         // 2048 float4
        int e = idx >> 5, c4 = idx & 31;
        float4 v = *(const float4*)(em2 + (size_t)(e0 + e) * 128 + c4 * 4);
        *(float4*)&x2f[e * 132 + c4 * 4] = v;
    }
    __syncthreads();

    // ---------- phase A2: pack x2 into fragment-pair layout xp2[hi][e][34] ----------
    {
        int part = tid >> 7;             // 0..3
        int sub  = tid & 127;
        int e = sub >> 1, hi2 = sub & 1;
        const float* xr = &x2f[e * 132];
        uint* dst = &xp2[(hi2 * 64 + e) * 34];
        if (part == 0) {                 // scalar part: 8 uints
            #pragma unroll
            for (int g = 0; g < 4; ++g)
                #pragma unroll
                for (int c = 0; c < 2; ++c) {
                    int v0 = 8 * g + 4 * hi2 + 2 * c;
                    dst[g * 2 + c] = packbf(xr[v0], xr[v0 + 1]);
                }
        } else {                         // vector part j = part-1: 8 uints
            int j = part - 1;
            #pragma unroll
            for (int g = 0; g < 4; ++g)
                #pragma unroll
                for (int c = 0; c < 2; ++c) {
                    int v0 = 8 * g + 4 * hi2 + 2 * c;
                    dst[8 + j * 8 + g * 2 + c] =
                        packbf(xr[32 + v0 * 3 + j], xr[32 + (v0 + 1) * 3 + j]);
                }
        }
    }
    __syncthreads();

    // ---------- phase B: ef -> scal cols 64..95 ----------
    #pragma unroll
    for (int q = 0; q < 4; ++q) {
        int idx = q * 512 + tid;         // 0..2047
        int e = idx >> 5, j = idx & 31;
        scal[e * 104 + 64 + j] = f2b(ef[(size_t)(e0 + e) * 32 + j]);
    }

    // ---------- MLP step 1: s_send/s_recv = nf @ Wn * S128 ----------
    {
        const int h = wv >> 2, eb = (wv & 3) * 16;
        const float* src = h ? nfr : nfs;
        const size_t erow = (size_t)(e0 + eb + l15) * 128;
        f32x4 acc1[2] = {{0,0,0,0},{0,0,0,0}};
        #pragma unroll
        for (int ks = 0; ks < 4; ++ks) {
            float4 va = *(const float4*)(src + erow + ks * 32 + lg * 8);
            float4 vb = *(const float4*)(src + erow + ks * 32 + lg * 8 + 4);
            bf16x8 a;
            a[0]=(short)f2b(va.x); a[1]=(short)f2b(va.y);
            a[2]=(short)f2b(va.z); a[3]=(short)f2b(va.w);
            a[4]=(short)f2b(vb.x); a[5]=(short)f2b(vb.y);
            a[6]=(short)f2b(vb.z); a[7]=(short)f2b(vb.w);
            #pragma unroll
            for (int nf = 0; nf < 2; ++nf) {
                bf16x8 b = *(const bf16x8*)(WnT + (nf * 16 + l15) * 128 + ks * 32 + lg * 8);
                acc1[nf] = __builtin_amdgcn_mfma_f32_16x16x32_bf16(a, b, acc1[nf], 0, 0, 0);
            }
        }
        #pragma unroll
        for (int nf = 0; nf < 2; ++nf)
            #pragma unroll
            for (int r = 0; r < 4; ++r)
                scal[(eb + lg * 4 + r) * 104 + h * 32 + nf * 16 + l15] =
                    f2b(acc1[nf][r] * S128);
    }
    __syncthreads();

    // ---------- MLP step 2: h1 = silu(scal @ W1 * S96) ----------
    {
        const int et = wv & 3, nh = wv >> 2;
        f32x4 acc2[4] = {{0,0,0,0},{0,0,0,0},{0,0,0,0},{0,0,0,0}};
        #pragma unroll
        for (int ks = 0; ks < 3; ++ks) {
            bf16x8 a = *(const bf16x8*)&scal[(et * 16 + l15) * 104 + ks * 32 + lg * 8];
            #pragma unroll
            for (int nf = 0; nf < 4; ++nf) {
                int gn = nh * 4 + nf;
                bf16x8 b = *(const bf16x8*)(W1T + (gn * 16 + l15) * 96 + ks * 32 + lg * 8);
                acc2[nf] = __builtin_amdgcn_mfma_f32_16x16x32_bf16(a, b, acc2[nf], 0, 0, 0);
            }
        }
        #pragma unroll
        for (int nf = 0; nf < 4; ++nf)
            #pragma unroll
            for (int r = 0; r < 4; ++r)
                h1b[(et * 16 + lg * 4 + r) * 136 + (nh * 4 + nf) * 16 + l15] =
                    f2b(silu_f(acc2[nf][r] * S96));
    }
    __syncthreads();

    // ---------- MLP step 3: h2 = silu(h1 @ W2 * S128) -> hbuf XOR-swizzled ----------
    {
        const int et = wv & 3, nh = wv >> 2;
        f32x4 acc3[4] = {{0,0,0,0},{0,0,0,0},{0,0,0,0},{0,0,0,0}};
        #pragma unroll
        for (int ks = 0; ks < 4; ++ks) {
            bf16x8 a = *(const bf16x8*)&h1b[(et * 16 + l15) * 136 + ks * 32 + lg * 8];
            #pragma unroll
            for (int nf = 0; nf < 4; ++nf) {
                int gn = nh * 4 + nf;
                bf16x8 b = *(const bf16x8*)(W2T + (gn * 16 + l15) * 128 + ks * 32 + lg * 8);
                acc3[nf] = __builtin_amdgcn_mfma_f32_16x16x32_bf16(a, b, acc3[nf], 0, 0, 0);
            }
        }
        #pragma unroll
        for (int nf = 0; nf < 4; ++nf)
            #pragma unroll
            for (int r = 0; r < 4; ++r) {
                int e = et * 16 + lg * 4 + r;
                int col = (nh * 4 + nf) * 16 + l15;
                hbuf[e * 128 + (col ^ ((e & 15) << 3))] =
                    f2b(silu_f(acc3[nf][r] * S128));
            }
    }
    __syncthreads();

    // ---------- GEMM v2: 20 (p,u)-units per wave, 32 m-rows x 64 edges ----------
    const int el = lane & 31;
    const int hi = lane >> 5;
    const int ew = hi * 32 + el;                    // e this lane writes
    const uint* xb0 = &xp2[(hi * 64 + el) * 34];        // group0: e = el
    const uint* xb1 = &xp2[(hi * 64 + 32 + el) * 34];   // group1: e = 32+el
    ushort* drow = &dlds[ew * 362];
    const int k0 = hi * 8;                          // k-offset within 16-step
    const int sw0 = (el & 15) << 3;                 // swizzle (same for e and e+32)

    #pragma unroll 1
    for (int un = 0; un < 20; ++un) {
        const int pu = wv * 20 + un;
        const int p = pu >> 5, u = pu & 31;

        bf16x8 a[8];
        const ushort* Ab = w3A + ((size_t)pu * 8 * 64 + lane) * 8;
        #pragma unroll
        for (int ks = 0; ks < 8; ++ks)
            a[ks] = *(const bf16x8*)(Ab + (size_t)ks * 512);

        f32x16 acc0 = {0,0,0,0,0,0,0,0,0,0,0,0,0,0,0,0};
        f32x16 acc1 = {0,0,0,0,0,0,0,0,0,0,0,0,0,0,0,0};
        #pragma unroll
        for (int ks = 0; ks < 8; ++ks) {
            int ko = (ks * 16 + k0) ^ sw0;
            bf16x8 b0 = *(const bf16x8*)&hbuf[el * 128 + ko];
            bf16x8 b1 = *(const bf16x8*)&hbuf[(32 + el) * 128 + ko];
            acc0 = __builtin_amdgcn_mfma_f32_32x32x16_bf16(a[ks], b0, acc0, 0, 0, 0);
            acc1 = __builtin_amdgcn_mfma_f32_32x32x16_bf16(a[ks], b1, acc1, 0, 0, 0);
        }

        // tail: d = sum_v w[u][v] * x2[v]  (v in C-rows; 1 shfl per value)
        if (p == 0 || p == 2) {
            const int off = (p == 0) ? 0 : 128;
            float s0 = 0.f, s1 = 0.f;
            #pragma unroll
            for (int g = 0; g < 4; ++g) {
                uint2 q0 = *(const uint2*)&xb0[g * 2];
                uint2 q1 = *(const uint2*)&xb1[g * 2];
                s0 += acc0[g*4+0]*blo(q0.x) + acc0[g*4+1]*bhi(q0.x)
                    + acc0[g*4+2]*blo(q0.y) + acc0[g*4+3]*bhi(q0.y);
                s1 += acc1[g*4+0]*blo(q1.x) + acc1[g*4+1]*bhi(q1.x)
                    + acc1[g*4+2]*blo(q1.y) + acc1[g*4+3]*bhi(q1.y);
            }
            s0 += __shfl_xor(s0, 32);
            s1 += __shfl_xor(s1, 32);
            drow[off + u] = f2b((hi ? s1 : s0) * S128);
        } else {
            const int off = ((p == 1) ? 32 : (p == 3) ? 160 : 256) + u * 3;
            #pragma unroll
            for (int j = 0; j < 3; ++j) {
                float s0 = 0.f, s1 = 0.f;
                #pragma unroll
                for (int g = 0; g < 4; ++g) {
                    uint2 q0 = *(const uint2*)&xb0[8 + j * 8 + g * 2];
                    uint2 q1 = *(const uint2*)&xb1[8 + j * 8 + g * 2];
                    s0 += acc0[g*4+0]*blo(q0.x) + acc0[g*4+1]*bhi(q0.x)
                        + acc0[g*4+2]*blo(q0.y) + acc0[g*4+3]*bhi(q0.y);
                    s1 += acc1[g*4+0]*blo(q1.x) + acc1[g*4+1]*bhi(q1.x)
                        + acc1[g*4+2]*blo(q1.y) + acc1[g*4+3]*bhi(q1.y);
                }
                s0 += __shfl_xor(s0, 32);
                s1 += __shfl_xor(s1, 32);
                drow[off + j] = f2b((hi ? s1 : s0) * S128);
            }
        }
    }
    __syncthreads();

    // ---------- stage x1 (em1) bf16 into hbuf [64][132] ----------
    {
        int e = tid >> 3, seg = tid & 7;
        const float* x1 = em1 + (size_t)(e0 + e) * 128 + seg * 16;
        #pragma unroll
        for (int q = 0; q < 4; ++q) {
            float4 v = *(const float4*)(x1 + q * 4);
            *(uint*)&hbuf[e * 132 + seg * 16 + q * 4]     = packbf(v.x, v.y);
            *(uint*)&hbuf[e * 132 + seg * 16 + q * 4 + 2] = packbf(v.z, v.w);
        }
    }
    __syncthreads();

    // ---------- finalize: c-values -> output matmuls via MFMA ----------
    #pragma unroll 1
    for (int it = 0; it < 4; ++it) {
        int unit = wv + 8 * it;
        if (unit >= 28) break;
        int mi = unit & 3, task = unit >> 2;
        int e = mi * 16 + l15;
        const ushort* de = &dlds[e * 362];
        const ushort* xe = &hbuf[e * 132];
        const size_t orow = (size_t)(e0 + mi * 16 + lg * 4) * 224;

        if (task == 0) {                       // out_0e: K = [c1|c4]
            bf16x8 af0, af1;
            #pragma unroll
            for (int t = 0; t < 8; ++t) {
                int u = lg * 8 + t;
                af0[t] = (short)f2b(S32 * b2f(xe[u]) * b2f(de[u]));
                float c4 = 0.f;
                #pragma unroll
                for (int i = 0; i < 3; ++i)
                    c4 += b2f(xe[32 + u * 3 + i]) * b2f(de[160 + u * 3 + i]);
                af1[t] = (short)f2b(c4 * S96);
            }
            #pragma unroll
            for (int nf = 0; nf < 2; ++nf) {
                bf16x8 bf0, bf1;
                #pragma unroll
                for (int t = 0; t < 8; ++t) {
                    bf0[t] = (short)f2b(W0e[(lg * 8 + t) * 32 + nf * 16 + l15]);
                    bf1[t] = (short)f2b(W0e[(32 + lg * 8 + t) * 32 + nf * 16 + l15]);
                }
                f32x4 o = {0.f, 0.f, 0.f, 0.f};
                o = __builtin_amdgcn_mfma_f32_16x16x32_bf16(af0, bf0, o, 0, 0, 0);
                o = __builtin_amdgcn_mfma_f32_16x16x32_bf16(af1, bf1, o, 0, 0, 0);
                #pragma unroll
                for (int rr = 0; rr < 4; ++rr)
                    out[orow + (size_t)rr * 224 + nf * 16 + l15] = o[rr] * S64;
            }
        } else if (task <= 3) {                // out_1o, j = task-1: K = [c2|c3]
            int j = task - 1;
            bf16x8 af0, af1;
            #pragma unroll
            for (int t = 0; t < 8; ++t) {
                int u = lg * 8 + t;
                af0[t] = (short)f2b(S32 * b2f(xe[u]) * b2f(de[32 + u * 3 + j]));
                af1[t] = (short)f2b(S32 * b2f(xe[32 + u * 3 + j]) * b2f(de[128 + u]));
            }
            #pragma unroll
            for (int nf = 0; nf < 2; ++nf) {
                bf16x8 bf0, bf1;
                #pragma unroll
                for (int t = 0; t < 8; ++t) {
                    bf0[t] = (short)f2b(W1o[(lg * 8 + t) * 32 + nf * 16 + l15]);
                    bf1[t] = (short)f2b(W1o[(32 + lg * 8 + t) * 32 + nf * 16 + l15]);
                }
                f32x4 o = {0.f, 0.f, 0.f, 0.f};
                o = __builtin_amdgcn_mfma_f32_16x16x32_bf16(af0, bf0, o, 0, 0, 0);
                o = __builtin_amdgcn_mfma_f32_16x16x32_bf16(af1, bf1, o, 0, 0, 0);
                #pragma unroll
                for (int rr = 0; rr < 4; ++rr)
                    out[orow + (size_t)rr * 224 + 32 + (nf * 16 + l15) * 3 + j] = o[rr] * S64;
            }
        } else {                               // out_1e, k = task-4: K = c5
            int k = task - 4;
            int k1 = k + 1; if (k1 > 2) k1 -= 3;
            int k2 = k + 2; if (k2 > 2) k2 -= 3;
            bf16x8 af0;
            #pragma unroll
            for (int t = 0; t < 8; ++t) {
                int u = lg * 8 + t;
                float a_ = b2f(xe[32 + u * 3 + k1]) * b2f(de[256 + u * 3 + k2])
                         - b2f(xe[32 + u * 3 + k2]) * b2f(de[256 + u * 3 + k1]);
                af0[t] = (short)f2b(a_ * S64);
            }
            #pragma unroll
            for (int nf = 0; nf < 2; ++nf) {
                bf16x8 bf0;
                #pragma unroll
                for (int t = 0; t < 8; ++t)
                    bf0[t] = (short)f2b(W1e[(lg * 8 + t) * 32 + nf * 16 + l15]);
                f32x4 o = {0.f, 0.f, 0.f, 0.f};
                o = __builtin_amdgcn_mfma_f32_16x16x32_bf16(af0, bf0, o, 0, 0, 0);
                #pragma unroll
                for (int rr = 0; rr < 4; ++rr)
                    out[orow + (size_t)rr * 224 + 128 + (nf * 16 + l15) * 3 + k] = o[rr] * S32;
            }
        }
    }
}

// ---------------------------------------------------------------------------
extern "C" void kernel_launch(void* const* d_in, const int* in_sizes, int n_in,
                              void* d_out, int out_size, void* d_ws, size_t ws_size,
                              hipStream_t stream) {
    const float* ef  = (const float*)d_in[0];
    const float* em1 = (const float*)d_in[1];
    const float* em2 = (const float*)d_in[2];
    const float* nfs = (const float*)d_in[3];
    const float* nfr = (const float*)d_in[4];
    const float* Wn  = (const float*)d_in[5];
    const float* W1  = (const float*)d_in[6];
    const float* W2  = (const float*)d_in[7];
    const float* W3  = (const float*)d_in[8];
    const float* W0e = (const float*)d_in[9];
    const float* W1o = (const float*)d_in[10];
    const float* W1e = (const float*)d_in[11];
    float* out = (float*)d_out;

    const int E = in_sizes[0] / 32;   // 40000

    // ws: w3A frag-major [160][8][64][8] bf16 | WnT | W1T | W2T
    char* ws = (char*)d_ws;
    ushort* w3A = (ushort*)ws;
    size_t off = (size_t)5120 * 128 * 2;
    ushort* WnT = (ushort*)(ws + off);  off += 32 * 128 * 2;
    ushort* W1T = (ushort*)(ws + off);  off += 128 * 96 * 2;
    ushort* W2T = (ushort*)(ws + off);

    prep_weights<<<128, 256, 0, stream>>>(Wn, W1, W2, WnT, W1T, W2T);
    w3_fragpack<<<160, 256, 0, stream>>>(W3, w3A);
    mega<<<E / 64, 512, 0, stream>>>(ef, em1, em2, nfs, nfr,
                                     WnT, W1T, W2T, w3A, W0e, W1o, W1e, out);
}

// Round 7
// 152.131 us; speedup vs baseline: 2.0540x; 1.1054x over previous
//
#include <hip/hip_runtime.h>
#include <hip/hip_bf16.h>
#include <math.h>

typedef __attribute__((ext_vector_type(8)))  short bf16x8;
typedef __attribute__((ext_vector_type(4)))  float f32x4;
typedef __attribute__((ext_vector_type(16))) float f32x16;

#define S128 0.08838834764831845f   // 1/sqrt(128)
#define S96  0.10206207261596575f   // 1/sqrt(96)
#define S32  0.17677669529663687f   // 1/sqrt(32)
#define S64  0.125f                 // 1/sqrt(64)
#define NE   40000

__device__ __forceinline__ float silu_f(float x){ return x / (1.0f + expf(-x)); }
__device__ __forceinline__ ushort f2b(float x){
    __hip_bfloat16 b = __float2bfloat16(x); return *(ushort*)&b;
}
__device__ __forceinline__ float b2f(ushort u){
    return __uint_as_float(((uint)u) << 16);
}
__device__ __forceinline__ float blo(uint d){ return __uint_as_float(d << 16); }
__device__ __forceinline__ float bhi(uint d){ return __uint_as_float(d & 0xffff0000u); }
__device__ __forceinline__ uint packbf(float a, float b){
    return (uint)f2b(a) | ((uint)f2b(b) << 16);
}

// ---------------------------------------------------------------------------
// prep: WnT [32][128], W1T [128][96], W2T [128][128] (bf16 transposes)
// ---------------------------------------------------------------------------
__global__ __launch_bounds__(256)
void prep_weights(const float* __restrict__ Wn, const float* __restrict__ W1,
                  const float* __restrict__ W2, ushort* __restrict__ WnT,
                  ushort* __restrict__ W1T, ushort* __restrict__ W2T) {
    int idx = blockIdx.x * 256 + threadIdx.x;   // 128 blocks -> 32768
    if (idx < 4096) {
        int n = idx >> 7, k = idx & 127;
        WnT[n * 128 + k] = f2b(Wn[k * 32 + n]);
    } else if (idx < 16384) {
        int t = idx - 4096; int n = t / 96, k = t - n * 96;
        W1T[n * 96 + k] = f2b(W1[k * 128 + n]);
    } else {
        int t = idx - 16384; int n = t >> 7, k = t & 127;
        W2T[n * 128 + k] = f2b(W2[k * 128 + n]);
    }
}

// ---------------------------------------------------------------------------
// W3 [128][5120] f32 -> w3A fragment-major bf16 (layout validated in R6):
//   w3A[pu*4096 + ks*512 + lane*8 + i] = W3[ks*16 + (lane>>5)*8 + i][pu*32 + (lane&31)]
// ---------------------------------------------------------------------------
__global__ __launch_bounds__(256)
void w3_fragpack(const float* __restrict__ W3, ushort* __restrict__ w3A) {
    const int pu = blockIdx.x;
    const int t  = threadIdx.x;
    #pragma unroll
    for (int s = 0; s < 2; ++s) {
        int slot = s * 256 + t;          // 0..511
        int ks = slot >> 6, l = slot & 63;
        int m = pu * 32 + (l & 31);
        int kbase = ks * 16 + (l >> 5) * 8;
        bf16x8 v;
        #pragma unroll
        for (int i = 0; i < 8; ++i)
            v[i] = (short)f2b(W3[(size_t)(kbase + i) * 5120 + m]);
        *(bf16x8*)&w3A[((size_t)(pu * 8 + ks) * 64 + l) * 8] = v;
    }
}

// ---------------------------------------------------------------------------
// MEGA2: MLP -> GEMM+contract -> d_t global (transposed, coalesced).
// 64 edges/block, 8 waves, LDS 47.1 KB, target 3 blocks/CU (6 waves/SIMD).
// d_t rows: p0: u | p1: 32+u*3+j | p2: 128+u | p3: 160+u*3+i | p4: 256+u*3+j
// ---------------------------------------------------------------------------
__global__ __launch_bounds__(512, 6)
void mega2(const float* __restrict__ ef,  const float* __restrict__ em2,
           const float* __restrict__ nfs, const float* __restrict__ nfr,
           const ushort* __restrict__ WnT, const ushort* __restrict__ W1T,
           const ushort* __restrict__ W2T, const ushort* __restrict__ w3A,
           ushort* __restrict__ dt)
{
    __shared__ __align__(16) ushort scratch[15360]; // 30720 B: scal|h1b, later xp2
    __shared__ __align__(16) ushort hbuf[64 * 128]; // 16384 B: h2 XOR-swizzled

    const int tid  = threadIdx.x;
    const int lane = tid & 63, wv = tid >> 6;
    const int l15  = lane & 15, lg = lane >> 4;
    const int e0   = blockIdx.x * 64;

    ushort* scal = scratch;          // [64][104]
    ushort* h1b  = scratch + 6656;   // [64][136]
    uint*   xp2  = (uint*)scratch;   // [2*64][34] (after MLP)

    // ---------- ef -> scal cols 64..95 ----------
    #pragma unroll
    for (int q = 0; q < 4; ++q) {
        int idx = q * 512 + tid;         // 0..2047
        int e = idx >> 5, j = idx & 31;
        scal[e * 104 + 64 + j] = f2b(ef[(size_t)(e0 + e) * 32 + j]);
    }

    // ---------- MLP step 1: s_send/s_recv = nf @ Wn * S128 ----------
    {
        const int h = wv >> 2, eb = (wv & 3) * 16;
        const float* src = h ? nfr : nfs;
        const size_t erow = (size_t)(e0 + eb + l15) * 128;
        f32x4 acc1[2] = {{0,0,0,0},{0,0,0,0}};
        #pragma unroll
        for (int ks = 0; ks < 4; ++ks) {
            float4 va = *(const float4*)(src + erow + ks * 32 + lg * 8);
            float4 vb = *(const float4*)(src + erow + ks * 32 + lg * 8 + 4);
            bf16x8 a;
            a[0]=(short)f2b(va.x); a[1]=(short)f2b(va.y);
            a[2]=(short)f2b(va.z); a[3]=(short)f2b(va.w);
            a[4]=(short)f2b(vb.x); a[5]=(short)f2b(vb.y);
            a[6]=(short)f2b(vb.z); a[7]=(short)f2b(vb.w);
            #pragma unroll
            for (int nf = 0; nf < 2; ++nf) {
                bf16x8 b = *(const bf16x8*)(WnT + (nf * 16 + l15) * 128 + ks * 32 + lg * 8);
                acc1[nf] = __builtin_amdgcn_mfma_f32_16x16x32_bf16(a, b, acc1[nf], 0, 0, 0);
            }
        }
        #pragma unroll
        for (int nf = 0; nf < 2; ++nf)
            #pragma unroll
            for (int r = 0; r < 4; ++r)
                scal[(eb + lg * 4 + r) * 104 + h * 32 + nf * 16 + l15] =
                    f2b(acc1[nf][r] * S128);
    }
    __syncthreads();

    // ---------- MLP step 2: h1 = silu(scal @ W1 * S96) ----------
    {
        const int et = wv & 3, nh = wv >> 2;
        f32x4 acc2[4] = {{0,0,0,0},{0,0,0,0},{0,0,0,0},{0,0,0,0}};
        #pragma unroll
        for (int ks = 0; ks < 3; ++ks) {
            bf16x8 a = *(const bf16x8*)&scal[(et * 16 + l15) * 104 + ks * 32 + lg * 8];
            #pragma unroll
            for (int nf = 0; nf < 4; ++nf) {
                int gn = nh * 4 + nf;
                bf16x8 b = *(const bf16x8*)(W1T + (gn * 16 + l15) * 96 + ks * 32 + lg * 8);
                acc2[nf] = __builtin_amdgcn_mfma_f32_16x16x32_bf16(a, b, acc2[nf], 0, 0, 0);
            }
        }
        #pragma unroll
        for (int nf = 0; nf < 4; ++nf)
            #pragma unroll
            for (int r = 0; r < 4; ++r)
                h1b[(et * 16 + lg * 4 + r) * 136 + (nh * 4 + nf) * 16 + l15] =
                    f2b(silu_f(acc2[nf][r] * S96));
    }
    __syncthreads();

    // ---------- MLP step 3: h2 = silu(h1 @ W2 * S128) -> hbuf XOR-swizzled ----------
    {
        const int et = wv & 3, nh = wv >> 2;
        f32x4 acc3[4] = {{0,0,0,0},{0,0,0,0},{0,0,0,0},{0,0,0,0}};
        #pragma unroll
        for (int ks = 0; ks < 4; ++ks) {
            bf16x8 a = *(const bf16x8*)&h1b[(et * 16 + l15) * 136 + ks * 32 + lg * 8];
            #pragma unroll
            for (int nf = 0; nf < 4; ++nf) {
                int gn = nh * 4 + nf;
                bf16x8 b = *(const bf16x8*)(W2T + (gn * 16 + l15) * 128 + ks * 32 + lg * 8);
                acc3[nf] = __builtin_amdgcn_mfma_f32_16x16x32_bf16(a, b, acc3[nf], 0, 0, 0);
            }
        }
        __syncthreads();   // h1b reads done before xp2 overwrites scratch
        #pragma unroll
        for (int nf = 0; nf < 4; ++nf)
            #pragma unroll
            for (int r = 0; r < 4; ++r) {
                int e = et * 16 + lg * 4 + r;
                int col = (nh * 4 + nf) * 16 + l15;
                hbuf[e * 128 + (col ^ ((e & 15) << 3))] =
                    f2b(silu_f(acc3[nf][r] * S128));
            }
    }

    // ---------- pack x2 (em2, from global) into xp2[hi][e][34] ----------
    {
        int part = tid >> 7;             // 0..3
        int sub  = tid & 127;
        int e = sub >> 1, hi2 = sub & 1;
        const float* xr = em2 + (size_t)(e0 + e) * 128;
        uint* dst = &xp2[(hi2 * 64 + e) * 34];
        if (part == 0) {                 // scalar part: 8 uints
            #pragma unroll
            for (int g = 0; g < 4; ++g)
                #pragma unroll
                for (int c = 0; c < 2; ++c) {
                    int v0 = 8 * g + 4 * hi2 + 2 * c;
                    float2 t1 = *(const float2*)(xr + v0);
                    dst[g * 2 + c] = packbf(t1.x, t1.y);
                }
        } else {                         // vector part j = part-1: 8 uints
            int j = part - 1;
            #pragma unroll
            for (int g = 0; g < 4; ++g)
                #pragma unroll
                for (int c = 0; c < 2; ++c) {
                    int v0 = 8 * g + 4 * hi2 + 2 * c;
                    dst[8 + j * 8 + g * 2 + c] =
                        packbf(xr[32 + v0 * 3 + j], xr[32 + (v0 + 1) * 3 + j]);
                }
        }
    }
    __syncthreads();

    // ---------- GEMM: per unit load a[8] once; per eh read B from LDS ----------
    const int el  = lane & 31;
    const int hi  = lane >> 5;
    const int sw0 = (el & 15) << 3;

    #pragma unroll 1
    for (int un = 0; un < 20; ++un) {
        const int pu = un * 8 + wv;
        const int p = pu >> 5, u = pu & 31;
        const ushort* Ab = w3A + (size_t)pu * 4096 + lane * 8;

        bf16x8 a[8];
        #pragma unroll
        for (int ks = 0; ks < 8; ++ks)
            a[ks] = *(const bf16x8*)(Ab + ks * 512);

        #pragma unroll 1
        for (int eh = 0; eh < 2; ++eh) {
            const int ebase = e0 + eh * 32;
            const ushort* hrow = &hbuf[(eh * 32 + el) * 128];
            f32x16 acc = {0,0,0,0,0,0,0,0,0,0,0,0,0,0,0,0};
            #pragma unroll
            for (int ks = 0; ks < 8; ++ks) {
                bf16x8 b = *(const bf16x8*)&hrow[(ks * 16 + hi * 8) ^ sw0];
                acc = __builtin_amdgcn_mfma_f32_32x32x16_bf16(a[ks], b, acc, 0, 0, 0);
            }
            const uint* xb = &xp2[(hi * 64 + eh * 32 + el) * 34];
            if (p == 0 || p == 2) {
                const int row = ((p == 0) ? 0 : 128) + u;
                float s = 0.f;
                #pragma unroll
                for (int g = 0; g < 4; ++g) {
                    uint2 q = *(const uint2*)&xb[g * 2];
                    s += acc[g*4+0]*blo(q.x) + acc[g*4+1]*bhi(q.x)
                       + acc[g*4+2]*blo(q.y) + acc[g*4+3]*bhi(q.y);
                }
                s += __shfl_xor(s, 32);
                if (hi == 0)
                    dt[(size_t)row * NE + ebase + el] = f2b(s * S128);
            } else {
                const int row0 = ((p == 1) ? 32 : (p == 3) ? 160 : 256) + u * 3;
                float sj[3];
                #pragma unroll
                for (int j = 0; j < 3; ++j) {
                    float s = 0.f;
                    #pragma unroll
                    for (int g = 0; g < 4; ++g) {
                        uint2 q = *(const uint2*)&xb[8 + j * 8 + g * 2];
                        s += acc[g*4+0]*blo(q.x) + acc[g*4+1]*bhi(q.x)
                           + acc[g*4+2]*blo(q.y) + acc[g*4+3]*bhi(q.y);
                    }
                    s += __shfl_xor(s, 32);
                    sj[j] = s;
                }
                if (hi == 0) {
                    #pragma unroll
                    for (int j = 0; j < 3; ++j)
                        dt[(size_t)(row0 + j) * NE + ebase + el] = f2b(sj[j] * S128);
                }
            }
        }
    }
}

// ---------------------------------------------------------------------------
// FINALIZE2: d_t + em1 -> c-values -> output matmuls. 32 edges/block, 4 waves.
// ---------------------------------------------------------------------------
__global__ __launch_bounds__(256)
void finalize2(const float* __restrict__ em1, const ushort* __restrict__ dt,
               const float* __restrict__ W0e, const float* __restrict__ W1o,
               const float* __restrict__ W1e, float* __restrict__ out)
{
    __shared__ __align__(16) ushort dl[352 * 33];   // 23232 B
    __shared__ __align__(16) ushort x1b[32 * 132];  // 8448 B
    const int tid  = threadIdx.x;
    const int lane = tid & 63, wv = tid >> 6;
    const int l15  = lane & 15, lg = lane >> 4;
    const int eb   = blockIdx.x * 32;

    // stage d_t tile (coalesced 64B rows)
    for (int idx = tid; idx < 352 * 32; idx += 256) {
        int row = idx >> 5, e = idx & 31;
        dl[row * 33 + e] = dt[(size_t)row * NE + eb + e];
    }
    // stage x1 (em1) packed bf16
    {
        int e = tid >> 3, seg = tid & 7;
        const float* x1 = em1 + (size_t)(eb + e) * 128 + seg * 16;
        #pragma unroll
        for (int q = 0; q < 4; ++q) {
            float4 v = *(const float4*)(x1 + q * 4);
            *(uint*)&x1b[e * 132 + seg * 16 + q * 4]     = packbf(v.x, v.y);
            *(uint*)&x1b[e * 132 + seg * 16 + q * 4 + 2] = packbf(v.z, v.w);
        }
    }
    __syncthreads();

    #pragma unroll 1
    for (int it = 0; it < 4; ++it) {
        int unit = it * 4 + wv;
        if (unit >= 14) break;
        int mi = unit & 1, task = unit >> 1;
        const int ei = mi * 16 + l15;
        const ushort* xe = &x1b[ei * 132];
        const size_t orow = (size_t)(eb + mi * 16 + lg * 4) * 224;

        if (task == 0) {                       // out_0e: K = [c1|c4]
            bf16x8 af0, af1;
            #pragma unroll
            for (int t = 0; t < 8; ++t) {
                int u = lg * 8 + t;
                af0[t] = (short)f2b(S32 * b2f(xe[u]) * b2f(dl[u * 33 + ei]));
                float c4 = 0.f;
                #pragma unroll
                for (int i = 0; i < 3; ++i)
                    c4 += b2f(xe[32 + u * 3 + i]) * b2f(dl[(160 + u * 3 + i) * 33 + ei]);
                af1[t] = (short)f2b(c4 * S96);
            }
            #pragma unroll
            for (int nf = 0; nf < 2; ++nf) {
                bf16x8 bf0, bf1;
                #pragma unroll
                for (int t = 0; t < 8; ++t) {
                    bf0[t] = (short)f2b(W0e[(lg * 8 + t) * 32 + nf * 16 + l15]);
                    bf1[t] = (short)f2b(W0e[(32 + lg * 8 + t) * 32 + nf * 16 + l15]);
                }
                f32x4 o = {0.f, 0.f, 0.f, 0.f};
                o = __builtin_amdgcn_mfma_f32_16x16x32_bf16(af0, bf0, o, 0, 0, 0);
                o = __builtin_amdgcn_mfma_f32_16x16x32_bf16(af1, bf1, o, 0, 0, 0);
                #pragma unroll
                for (int rr = 0; rr < 4; ++rr)
                    out[orow + (size_t)rr * 224 + nf * 16 + l15] = o[rr] * S64;
            }
        } else if (task <= 3) {                // out_1o, j = task-1: K = [c2|c3]
            int j = task - 1;
            bf16x8 af0, af1;
            #pragma unroll
            for (int t = 0; t < 8; ++t) {
                int u = lg * 8 + t;
                af0[t] = (short)f2b(S32 * b2f(xe[u]) * b2f(dl[(32 + u * 3 + j) * 33 + ei]));
                af1[t] = (short)f2b(S32 * b2f(xe[32 + u * 3 + j]) * b2f(dl[(128 + u) * 33 + ei]));
            }
            #pragma unroll
            for (int nf = 0; nf < 2; ++nf) {
                bf16x8 bf0, bf1;
                #pragma unroll
                for (int t = 0; t < 8; ++t) {
                    bf0[t] = (short)f2b(W1o[(lg * 8 + t) * 32 + nf * 16 + l15]);
                    bf1[t] = (short)f2b(W1o[(32 + lg * 8 + t) * 32 + nf * 16 + l15]);
                }
                f32x4 o = {0.f, 0.f, 0.f, 0.f};
                o = __builtin_amdgcn_mfma_f32_16x16x32_bf16(af0, bf0, o, 0, 0, 0);
                o = __builtin_amdgcn_mfma_f32_16x16x32_bf16(af1, bf1, o, 0, 0, 0);
                #pragma unroll
                for (int rr = 0; rr < 4; ++rr)
                    out[orow + (size_t)rr * 224 + 32 + (nf * 16 + l15) * 3 + j] = o[rr] * S64;
            }
        } else {                               // out_1e, k = task-4: K = c5
            int k = task - 4;
            int k1 = k + 1; if (k1 > 2) k1 -= 3;
            int k2 = k + 2; if (k2 > 2) k2 -= 3;
            bf16x8 af0;
            #pragma unroll
            for (int t = 0; t < 8; ++t) {
                int u = lg * 8 + t;
                float a_ = b2f(xe[32 + u * 3 + k1]) * b2f(dl[(256 + u * 3 + k2) * 33 + ei])
                         - b2f(xe[32 + u * 3 + k2]) * b2f(dl[(256 + u * 3 + k1) * 33 + ei]);
                af0[t] = (short)f2b(a_ * S64);
            }
            #pragma unroll
            for (int nf = 0; nf < 2; ++nf) {
                bf16x8 bf0;
                #pragma unroll
                for (int t = 0; t < 8; ++t)
                    bf0[t] = (short)f2b(W1e[(lg * 8 + t) * 32 + nf * 16 + l15]);
                f32x4 o = {0.f, 0.f, 0.f, 0.f};
                o = __builtin_amdgcn_mfma_f32_16x16x32_bf16(af0, bf0, o, 0, 0, 0);
                #pragma unroll
                for (int rr = 0; rr < 4; ++rr)
                    out[orow + (size_t)rr * 224 + 128 + (nf * 16 + l15) * 3 + k] = o[rr] * S32;
            }
        }
    }
}

// ---------------------------------------------------------------------------
extern "C" void kernel_launch(void* const* d_in, const int* in_sizes, int n_in,
                              void* d_out, int out_size, void* d_ws, size_t ws_size,
                              hipStream_t stream) {
    const float* ef  = (const float*)d_in[0];
    const float* em1 = (const float*)d_in[1];
    const float* em2 = (const float*)d_in[2];
    const float* nfs = (const float*)d_in[3];
    const float* nfr = (const float*)d_in[4];
    const float* Wn  = (const float*)d_in[5];
    const float* W1  = (const float*)d_in[6];
    const float* W2  = (const float*)d_in[7];
    const float* W3  = (const float*)d_in[8];
    const float* W0e = (const float*)d_in[9];
    const float* W1o = (const float*)d_in[10];
    const float* W1e = (const float*)d_in[11];
    float* out = (float*)d_out;

    const int E = in_sizes[0] / 32;   // 40000

    // ws: w3A [160*8*64*8] | WnT | W1T | W2T | d_t [352][E]
    char* ws = (char*)d_ws;
    ushort* w3A = (ushort*)ws;
    size_t off = (size_t)5120 * 128 * 2;
    ushort* WnT = (ushort*)(ws + off);  off += 32 * 128 * 2;
    ushort* W1T = (ushort*)(ws + off);  off += 128 * 96 * 2;
    ushort* W2T = (ushort*)(ws + off);  off += 128 * 128 * 2;
    ushort* dt  = (ushort*)(ws + off);  // 352 * E * 2 = 28.2 MB

    prep_weights<<<128, 256, 0, stream>>>(Wn, W1, W2, WnT, W1T, W2T);
    w3_fragpack<<<160, 256, 0, stream>>>(W3, w3A);
    mega2<<<E / 64, 512, 0, stream>>>(ef, em2, nfs, nfr,
                                      WnT, W1T, W2T, w3A, dt);
    finalize2<<<E / 32, 256, 0, stream>>>(em1, dt, W0e, W1o, W1e, out);
}